// Round 1
// baseline (622.076 us; speedup 1.0000x reference)
//
#include <hip/hip_runtime.h>
#include <math.h>

// SensorGNN: 2-layer GCN (N=50000, E=800000, F=128, H=64) + flat classifier (6 classes).
// Pipeline: deg histogram -> prefix scan -> CSR scatter -> [gemm+dinv-scale -> csr-aggregate]x2
//           -> classifier dot -> softmax.
// All f32. Feature buffers (12.8MB) stay L2/L3 resident for the gather phase.

// ---------------- graph build ----------------

__global__ void count_deg(const int* __restrict__ dst, int* __restrict__ deg, int E) {
  int i = blockIdx.x * blockDim.x + threadIdx.x;
  if (i < E) atomicAdd(&deg[dst[i]], 1);
}

// per-256-chunk exclusive scan; bsum[block]=chunk total; dinv = rsqrt(deg+1) (self loop)
__global__ void scan_block(const int* __restrict__ deg, int* __restrict__ offs,
                           int* __restrict__ bsum, float* __restrict__ dinv, int N) {
  int tid = threadIdx.x, lane = tid & 63, wv = tid >> 6;
  int i = blockIdx.x * 256 + tid;
  int v = (i < N) ? deg[i] : 0;
  if (i < N) dinv[i] = rsqrtf((float)(v + 1));
  int x = v;
#pragma unroll
  for (int d = 1; d < 64; d <<= 1) {
    int y = __shfl_up(x, d, 64);
    if (lane >= d) x += y;
  }
  __shared__ int wtot[4];
  __shared__ int woff[4];
  if (lane == 63) wtot[wv] = x;
  __syncthreads();
  if (tid == 0) {
    int s = 0;
    for (int w = 0; w < 4; ++w) { woff[w] = s; s += wtot[w]; }
    bsum[blockIdx.x] = s;
  }
  __syncthreads();
  if (i < N) offs[i] = x - v + woff[wv];
}

// single block: exclusive-scan bsum[nb] in place (nb <= 256), total -> offs[N]
__global__ void scan_bsums(int* __restrict__ bsum, int* __restrict__ offs, int nb, int N) {
  int tid = threadIdx.x, lane = tid & 63, wv = tid >> 6;
  int v = (tid < nb) ? bsum[tid] : 0;
  int x = v;
#pragma unroll
  for (int d = 1; d < 64; d <<= 1) {
    int y = __shfl_up(x, d, 64);
    if (lane >= d) x += y;
  }
  __shared__ int wtot[4];
  __shared__ int woff[4];
  if (lane == 63) wtot[wv] = x;
  __syncthreads();
  if (tid == 0) {
    int s = 0;
    for (int w = 0; w < 4; ++w) { woff[w] = s; s += wtot[w]; }
  }
  __syncthreads();
  int excl = x - v + woff[wv];
  if (tid < nb) bsum[tid] = excl;
  if (tid == nb - 1) offs[N] = excl + v;
}

__global__ void scan_add(int* __restrict__ offs, const int* __restrict__ bsum,
                         int* __restrict__ cursor, int N) {
  int i = blockIdx.x * 256 + threadIdx.x;
  if (i < N) {
    int o = offs[i] + bsum[blockIdx.x];
    offs[i] = o;
    cursor[i] = o;
  }
}

__global__ void scatter_edges(const int* __restrict__ src, const int* __restrict__ dst,
                              int* __restrict__ cursor, int* __restrict__ srt, int E) {
  int i = blockIdx.x * blockDim.x + threadIdx.x;
  if (i < E) {
    int p = atomicAdd(&cursor[dst[i]], 1);
    srt[p] = src[i];
  }
}

// ---------------- dense transform: G = (X @ W) * dinv[row] ----------------
// block = 256 (4 waves), 16 rows/block, each wave computes 4 rows x 64 cols.

template <int K>
__global__ __launch_bounds__(256) void gemm_scale(
    const float* __restrict__ X, const float* __restrict__ W,
    const float* __restrict__ dinv, float* __restrict__ G, int N) {
  __shared__ float smw[K * 64];
  __shared__ float xs[16 * K];
  int tid = threadIdx.x, lane = tid & 63, wv = tid >> 6;
  for (int idx = tid; idx < K * 64; idx += 256) smw[idx] = W[idx];
  int row0 = blockIdx.x * 16;
  int base = row0 * K;
  int count = min(16 * K, N * K - base);
  for (int idx = tid; idx < count; idx += 256) xs[idx] = X[base + idx];
  __syncthreads();

  float acc[4] = {0.f, 0.f, 0.f, 0.f};
  const float* xr = &xs[(wv * 4) * K];
#pragma unroll
  for (int k = 0; k < K; ++k) {
    float wval = smw[k * 64 + lane];
#pragma unroll
    for (int r = 0; r < 4; ++r) acc[r] = fmaf(xr[r * K + k], wval, acc[r]);
  }
#pragma unroll
  for (int r = 0; r < 4; ++r) {
    int row = row0 + wv * 4 + r;
    if (row < N) G[(size_t)row * 64 + lane] = acc[r] * dinv[row];
  }
}

// ---------------- aggregation: H[d] = relu(dinv[d]*(G[d] + sum_{s in in(d)} G[s]) + b) ----
// one wave per node; lane = feature.

__global__ __launch_bounds__(256) void aggregate(
    const float* __restrict__ G, const int* __restrict__ offs,
    const int* __restrict__ srt, const float* __restrict__ dinv,
    const float* __restrict__ bias, float* __restrict__ H, int N) {
  int lane = threadIdx.x & 63, wv = threadIdx.x >> 6;
  int node = blockIdx.x * 4 + wv;
  if (node >= N) return;
  float acc = G[(size_t)node * 64 + lane];  // self loop
  int e = offs[node], e1 = offs[node + 1];
  for (; e + 1 < e1; e += 2) {
    int s0 = srt[e], s1 = srt[e + 1];
    acc += G[(size_t)s0 * 64 + lane] + G[(size_t)s1 * 64 + lane];
  }
  if (e < e1) acc += G[(size_t)srt[e] * 64 + lane];
  float r = fmaf(acc, dinv[node], bias[lane]);
  H[(size_t)node * 64 + lane] = fmaxf(r, 0.f);
}

// ---------------- classifier partial dots: acc6[c] += sum_i H[i]*Wc[i*6+c] ----------------

__global__ __launch_bounds__(256) void classifier(
    const float* __restrict__ H, const float* __restrict__ Wc,
    float* __restrict__ acc6, int M) {
  float a[6] = {0.f, 0.f, 0.f, 0.f, 0.f, 0.f};
  int stride = gridDim.x * blockDim.x;
  for (int i = blockIdx.x * blockDim.x + threadIdx.x; i < M; i += stride) {
    float h = H[i];
    const float* w = Wc + (size_t)i * 6;
#pragma unroll
    for (int c = 0; c < 6; ++c) a[c] = fmaf(h, w[c], a[c]);
  }
#pragma unroll
  for (int c = 0; c < 6; ++c) {
    for (int d = 32; d > 0; d >>= 1) a[c] += __shfl_down(a[c], d, 64);
  }
  __shared__ float sh[4][6];
  int lane = threadIdx.x & 63, wv = threadIdx.x >> 6;
  if (lane == 0) {
#pragma unroll
    for (int c = 0; c < 6; ++c) sh[wv][c] = a[c];
  }
  __syncthreads();
  if (threadIdx.x == 0) {
#pragma unroll
    for (int c = 0; c < 6; ++c) {
      float t = sh[0][c] + sh[1][c] + sh[2][c] + sh[3][c];
      atomicAdd(&acc6[c], t);
    }
  }
}

__global__ void softmax6(const float* __restrict__ acc6, const float* __restrict__ bc,
                         float* __restrict__ out) {
  if (threadIdx.x == 0) {
    float l[6], m = -1e30f;
#pragma unroll
    for (int c = 0; c < 6; ++c) { l[c] = acc6[c] + bc[c]; m = fmaxf(m, l[c]); }
    float s = 0.f;
#pragma unroll
    for (int c = 0; c < 6; ++c) { l[c] = __expf(l[c] - m); s += l[c]; }
    float inv = 1.f / s;
#pragma unroll
    for (int c = 0; c < 6; ++c) out[c] = l[c] * inv;
  }
}

// ---------------- launch ----------------

extern "C" void kernel_launch(void* const* d_in, const int* in_sizes, int n_in,
                              void* d_out, int out_size, void* d_ws, size_t ws_size,
                              hipStream_t stream) {
  const float* x  = (const float*)d_in[0];
  const int*   ei = (const int*)d_in[1];
  const float* W1 = (const float*)d_in[2];
  const float* b1 = (const float*)d_in[3];
  const float* W2 = (const float*)d_in[4];
  const float* b2 = (const float*)d_in[5];
  const float* Wc = (const float*)d_in[6];
  const float* bc = (const float*)d_in[7];
  float* out = (float*)d_out;

  const int N = in_sizes[0] / 128;  // 50000
  const int E = in_sizes[1] / 2;    // 800000
  const int* esrc = ei;
  const int* edst = ei + E;
  const int nb = (N + 255) / 256;   // 196 (<=256 required by scan_bsums)

  int* deg    = (int*)d_ws;
  int* offs   = deg + N;            // N+1
  int* cursor = offs + N + 1;
  int* srt    = cursor + N;         // E
  int* bsum   = srt + E;            // nb
  float* dinv = (float*)(bsum + nb);
  float* bufA = dinv + N;                      // N*64  (scaled transform g)
  float* bufB = bufA + (size_t)N * 64;         // N*64  (aggregated h)
  float* acc6 = bufB + (size_t)N * 64;         // 6

  hipMemsetAsync(deg, 0, (size_t)N * sizeof(int), stream);
  hipMemsetAsync(acc6, 0, 6 * sizeof(float), stream);

  count_deg<<<(E + 255) / 256, 256, 0, stream>>>(edst, deg, E);
  scan_block<<<nb, 256, 0, stream>>>(deg, offs, bsum, dinv, N);
  scan_bsums<<<1, 256, 0, stream>>>(bsum, offs, nb, N);
  scan_add<<<nb, 256, 0, stream>>>(offs, bsum, cursor, N);
  scatter_edges<<<(E + 255) / 256, 256, 0, stream>>>(esrc, edst, cursor, srt, E);

  gemm_scale<128><<<(N + 15) / 16, 256, 0, stream>>>(x, W1, dinv, bufA, N);
  aggregate<<<(N + 3) / 4, 256, 0, stream>>>(bufA, offs, srt, dinv, b1, bufB, N);
  gemm_scale<64><<<(N + 15) / 16, 256, 0, stream>>>(bufB, W2, dinv, bufA, N);
  aggregate<<<(N + 3) / 4, 256, 0, stream>>>(bufA, offs, srt, dinv, b2, bufB, N);

  classifier<<<2048, 256, 0, stream>>>(bufB, Wc, acc6, N * 64);
  softmax6<<<1, 64, 0, stream>>>(acc6, bc, out);
}

// Round 2
// 421.936 us; speedup vs baseline: 1.4743x; 1.4743x over previous
//
#include <hip/hip_runtime.h>
#include <math.h>

// SensorGNN: 2-layer GCN (N=50000, E=800000, F=128, H=64) + flat classifier (6 classes).
// Pipeline: deg histogram -> prefix scan -> CSR scatter -> [gemm+dinv-scale -> csr-aggregate]x2
//           -> classifier dot -> softmax.
// All f32. Feature buffers (12.8MB) stay L2/L3 resident for the gather phase.

// ---------------- graph build ----------------

__global__ void count_deg(const int* __restrict__ dst, int* __restrict__ deg, int E) {
  int i = blockIdx.x * blockDim.x + threadIdx.x;
  if (i < E) atomicAdd(&deg[dst[i]], 1);
}

// per-256-chunk exclusive scan; bsum[block]=chunk total; dinv = rsqrt(deg+1) (self loop)
__global__ void scan_block(const int* __restrict__ deg, int* __restrict__ offs,
                           int* __restrict__ bsum, float* __restrict__ dinv, int N) {
  int tid = threadIdx.x, lane = tid & 63, wv = tid >> 6;
  int i = blockIdx.x * 256 + tid;
  int v = (i < N) ? deg[i] : 0;
  if (i < N) dinv[i] = rsqrtf((float)(v + 1));
  int x = v;
#pragma unroll
  for (int d = 1; d < 64; d <<= 1) {
    int y = __shfl_up(x, d, 64);
    if (lane >= d) x += y;
  }
  __shared__ int wtot[4];
  __shared__ int woff[4];
  if (lane == 63) wtot[wv] = x;
  __syncthreads();
  if (tid == 0) {
    int s = 0;
    for (int w = 0; w < 4; ++w) { woff[w] = s; s += wtot[w]; }
    bsum[blockIdx.x] = s;
  }
  __syncthreads();
  if (i < N) offs[i] = x - v + woff[wv];
}

// single block: exclusive-scan bsum[nb] in place (nb <= 256), total -> offs[N]
__global__ void scan_bsums(int* __restrict__ bsum, int* __restrict__ offs, int nb, int N) {
  int tid = threadIdx.x, lane = tid & 63, wv = tid >> 6;
  int v = (tid < nb) ? bsum[tid] : 0;
  int x = v;
#pragma unroll
  for (int d = 1; d < 64; d <<= 1) {
    int y = __shfl_up(x, d, 64);
    if (lane >= d) x += y;
  }
  __shared__ int wtot[4];
  __shared__ int woff[4];
  if (lane == 63) wtot[wv] = x;
  __syncthreads();
  if (tid == 0) {
    int s = 0;
    for (int w = 0; w < 4; ++w) { woff[w] = s; s += wtot[w]; }
  }
  __syncthreads();
  int excl = x - v + woff[wv];
  if (tid < nb) bsum[tid] = excl;
  if (tid == nb - 1) offs[N] = excl + v;
}

__global__ void scan_add(int* __restrict__ offs, const int* __restrict__ bsum,
                         int* __restrict__ cursor, int N) {
  int i = blockIdx.x * 256 + threadIdx.x;
  if (i < N) {
    int o = offs[i] + bsum[blockIdx.x];
    offs[i] = o;
    cursor[i] = o;
  }
}

__global__ void scatter_edges(const int* __restrict__ src, const int* __restrict__ dst,
                              int* __restrict__ cursor, int* __restrict__ srt, int E) {
  int i = blockIdx.x * blockDim.x + threadIdx.x;
  if (i < E) {
    int p = atomicAdd(&cursor[dst[i]], 1);
    srt[p] = src[i];
  }
}

// ---------------- dense transform: G = (X @ W) * dinv[row] ----------------
// block = 256 (4 waves), 32 rows/block, each wave computes 8 rows x 64 cols.
// Unroll capped at 4 to avoid the round-1 VGPR blowup (256 VGPR + 380MB scratch spill).

template <int K, int ROWS>
__global__ __launch_bounds__(256) void gemm_scale(
    const float* __restrict__ X, const float* __restrict__ W,
    const float* __restrict__ dinv, float* __restrict__ G, int N) {
  __shared__ float smw[K * 64];
  __shared__ float xs[ROWS * K];
  int tid = threadIdx.x, lane = tid & 63, wv = tid >> 6;
  for (int idx = tid; idx < K * 16; idx += 256)
    ((float4*)smw)[idx] = ((const float4*)W)[idx];
  int row0 = blockIdx.x * ROWS;
  int base = row0 * K;
  int cnt4 = (min(ROWS * K, N * K - base)) >> 2;  // K%4==0 so exact
  const float4* X4 = (const float4*)(X + base);
  for (int idx = tid; idx < cnt4; idx += 256) ((float4*)xs)[idx] = X4[idx];
  __syncthreads();

  constexpr int RW = ROWS / 4;  // rows per wave
  float acc[RW];
#pragma unroll
  for (int r = 0; r < RW; ++r) acc[r] = 0.f;
  const float* xr = &xs[(wv * RW) * K];
#pragma unroll 4
  for (int k = 0; k < K; ++k) {
    float wval = smw[k * 64 + lane];  // lane-contiguous: 2-way bank alias = free
#pragma unroll
    for (int r = 0; r < RW; ++r) acc[r] = fmaf(xr[r * K + k], wval, acc[r]);  // LDS broadcast
  }
#pragma unroll
  for (int r = 0; r < RW; ++r) {
    int row = row0 + wv * RW + r;
    if (row < N) G[(size_t)row * 64 + lane] = acc[r] * dinv[row];
  }
}

// ---------------- aggregation: H[d] = relu(dinv[d]*(G[d] + sum_{s in in(d)} G[s]) + b) ----
// one wave per node; lane = feature.

__global__ __launch_bounds__(256) void aggregate(
    const float* __restrict__ G, const int* __restrict__ offs,
    const int* __restrict__ srt, const float* __restrict__ dinv,
    const float* __restrict__ bias, float* __restrict__ H, int N) {
  int lane = threadIdx.x & 63, wv = threadIdx.x >> 6;
  int node = blockIdx.x * 4 + wv;
  if (node >= N) return;
  float acc = G[(size_t)node * 64 + lane];  // self loop
  int e = offs[node], e1 = offs[node + 1];
  for (; e + 1 < e1; e += 2) {
    int s0 = srt[e], s1 = srt[e + 1];
    acc += G[(size_t)s0 * 64 + lane] + G[(size_t)s1 * 64 + lane];
  }
  if (e < e1) acc += G[(size_t)srt[e] * 64 + lane];
  float r = fmaf(acc, dinv[node], bias[lane]);
  H[(size_t)node * 64 + lane] = fmaxf(r, 0.f);
}

// ---------------- classifier partial dots: acc6[c] += sum_i H[i]*Wc[i*6+c] ----------------

__global__ __launch_bounds__(256) void classifier(
    const float* __restrict__ H, const float* __restrict__ Wc,
    float* __restrict__ acc6, int M) {
  float a[6] = {0.f, 0.f, 0.f, 0.f, 0.f, 0.f};
  int stride = gridDim.x * blockDim.x;
  for (int i = blockIdx.x * blockDim.x + threadIdx.x; i < M; i += stride) {
    float h = H[i];
    const float* w = Wc + (size_t)i * 6;
#pragma unroll
    for (int c = 0; c < 6; ++c) a[c] = fmaf(h, w[c], a[c]);
  }
#pragma unroll
  for (int c = 0; c < 6; ++c) {
    for (int d = 32; d > 0; d >>= 1) a[c] += __shfl_down(a[c], d, 64);
  }
  __shared__ float sh[4][6];
  int lane = threadIdx.x & 63, wv = threadIdx.x >> 6;
  if (lane == 0) {
#pragma unroll
    for (int c = 0; c < 6; ++c) sh[wv][c] = a[c];
  }
  __syncthreads();
  if (threadIdx.x == 0) {
#pragma unroll
    for (int c = 0; c < 6; ++c) {
      float t = sh[0][c] + sh[1][c] + sh[2][c] + sh[3][c];
      atomicAdd(&acc6[c], t);
    }
  }
}

__global__ void softmax6(const float* __restrict__ acc6, const float* __restrict__ bc,
                         float* __restrict__ out) {
  if (threadIdx.x == 0) {
    float l[6], m = -1e30f;
#pragma unroll
    for (int c = 0; c < 6; ++c) { l[c] = acc6[c] + bc[c]; m = fmaxf(m, l[c]); }
    float s = 0.f;
#pragma unroll
    for (int c = 0; c < 6; ++c) { l[c] = __expf(l[c] - m); s += l[c]; }
    float inv = 1.f / s;
#pragma unroll
    for (int c = 0; c < 6; ++c) out[c] = l[c] * inv;
  }
}

// ---------------- launch ----------------

extern "C" void kernel_launch(void* const* d_in, const int* in_sizes, int n_in,
                              void* d_out, int out_size, void* d_ws, size_t ws_size,
                              hipStream_t stream) {
  const float* x  = (const float*)d_in[0];
  const int*   ei = (const int*)d_in[1];
  const float* W1 = (const float*)d_in[2];
  const float* b1 = (const float*)d_in[3];
  const float* W2 = (const float*)d_in[4];
  const float* b2 = (const float*)d_in[5];
  const float* Wc = (const float*)d_in[6];
  const float* bc = (const float*)d_in[7];
  float* out = (float*)d_out;

  const int N = in_sizes[0] / 128;  // 50000
  const int E = in_sizes[1] / 2;    // 800000
  const int* esrc = ei;
  const int* edst = ei + E;
  const int nb = (N + 255) / 256;   // 196 (<=256 required by scan_bsums)

  int* deg    = (int*)d_ws;
  int* offs   = deg + N;            // N+1
  int* cursor = offs + N + 1;
  int* srt    = cursor + N;         // E
  int* bsum   = srt + E;            // nb
  float* dinv = (float*)(bsum + nb);
  float* bufA = dinv + N;                      // N*64  (scaled transform g)
  float* bufB = bufA + (size_t)N * 64;         // N*64  (aggregated h)
  float* acc6 = bufB + (size_t)N * 64;         // 6

  hipMemsetAsync(deg, 0, (size_t)N * sizeof(int), stream);
  hipMemsetAsync(acc6, 0, 6 * sizeof(float), stream);

  count_deg<<<(E + 255) / 256, 256, 0, stream>>>(edst, deg, E);
  scan_block<<<nb, 256, 0, stream>>>(deg, offs, bsum, dinv, N);
  scan_bsums<<<1, 256, 0, stream>>>(bsum, offs, nb, N);
  scan_add<<<nb, 256, 0, stream>>>(offs, bsum, cursor, N);
  scatter_edges<<<(E + 255) / 256, 256, 0, stream>>>(esrc, edst, cursor, srt, E);

  gemm_scale<128, 32><<<(N + 31) / 32, 256, 0, stream>>>(x, W1, dinv, bufA, N);
  aggregate<<<(N + 3) / 4, 256, 0, stream>>>(bufA, offs, srt, dinv, b1, bufB, N);
  gemm_scale<64, 32><<<(N + 31) / 32, 256, 0, stream>>>(bufB, W2, dinv, bufA, N);
  aggregate<<<(N + 3) / 4, 256, 0, stream>>>(bufA, offs, srt, dinv, b2, bufB, N);

  classifier<<<2048, 256, 0, stream>>>(bufB, Wc, acc6, N * 64);
  softmax6<<<1, 64, 0, stream>>>(acc6, bc, out);
}

// Round 3
// 402.682 us; speedup vs baseline: 1.5448x; 1.0478x over previous
//
#include <hip/hip_runtime.h>
#include <math.h>

// SensorGNN: 2-layer GCN (N=50000, E=800000, F=128, H=64) + flat classifier (6 classes).
// Pipeline: deg histogram -> prefix scan -> CSR scatter -> [gemm+dinv-scale -> csr-aggregate]x2
//           -> classifier dot -> softmax.
// All f32. Feature buffers (12.8MB) stay L2/L3 resident for the gather phase.

// ---------------- graph build ----------------

__global__ void count_deg(const int* __restrict__ dst, int* __restrict__ deg, int E) {
  int i = blockIdx.x * blockDim.x + threadIdx.x;
  if (i < E) atomicAdd(&deg[dst[i]], 1);
}

// per-256-chunk exclusive scan; bsum[block]=chunk total; dinv = rsqrt(deg+1) (self loop)
__global__ void scan_block(const int* __restrict__ deg, int* __restrict__ offs,
                           int* __restrict__ bsum, float* __restrict__ dinv, int N) {
  int tid = threadIdx.x, lane = tid & 63, wv = tid >> 6;
  int i = blockIdx.x * 256 + tid;
  int v = (i < N) ? deg[i] : 0;
  if (i < N) dinv[i] = rsqrtf((float)(v + 1));
  int x = v;
#pragma unroll
  for (int d = 1; d < 64; d <<= 1) {
    int y = __shfl_up(x, d, 64);
    if (lane >= d) x += y;
  }
  __shared__ int wtot[4];
  __shared__ int woff[4];
  if (lane == 63) wtot[wv] = x;
  __syncthreads();
  if (tid == 0) {
    int s = 0;
    for (int w = 0; w < 4; ++w) { woff[w] = s; s += wtot[w]; }
    bsum[blockIdx.x] = s;
  }
  __syncthreads();
  if (i < N) offs[i] = x - v + woff[wv];
}

// single block: exclusive-scan bsum[nb] in place (nb <= 256), total -> offs[N]
__global__ void scan_bsums(int* __restrict__ bsum, int* __restrict__ offs, int nb, int N) {
  int tid = threadIdx.x, lane = tid & 63, wv = tid >> 6;
  int v = (tid < nb) ? bsum[tid] : 0;
  int x = v;
#pragma unroll
  for (int d = 1; d < 64; d <<= 1) {
    int y = __shfl_up(x, d, 64);
    if (lane >= d) x += y;
  }
  __shared__ int wtot[4];
  __shared__ int woff[4];
  if (lane == 63) wtot[wv] = x;
  __syncthreads();
  if (tid == 0) {
    int s = 0;
    for (int w = 0; w < 4; ++w) { woff[w] = s; s += wtot[w]; }
  }
  __syncthreads();
  int excl = x - v + woff[wv];
  if (tid < nb) bsum[tid] = excl;
  if (tid == nb - 1) offs[N] = excl + v;
}

__global__ void scan_add(int* __restrict__ offs, const int* __restrict__ bsum,
                         int* __restrict__ cursor, int N) {
  int i = blockIdx.x * 256 + threadIdx.x;
  if (i < N) {
    int o = offs[i] + bsum[blockIdx.x];
    offs[i] = o;
    cursor[i] = o;
  }
}

__global__ void scatter_edges(const int* __restrict__ src, const int* __restrict__ dst,
                              int* __restrict__ cursor, int* __restrict__ srt, int E) {
  int i = blockIdx.x * blockDim.x + threadIdx.x;
  if (i < E) {
    int p = atomicAdd(&cursor[dst[i]], 1);
    srt[p] = src[i];
  }
}

// ---------------- dense transform: G = (X @ W) * dinv[row] ----------------
// block = 256 (4 waves), 32 rows/block, each wave computes 8 rows x 64 cols.
// Unroll capped at 4 to avoid the round-1 VGPR blowup (256 VGPR + 380MB scratch spill).

template <int K, int ROWS>
__global__ __launch_bounds__(256) void gemm_scale(
    const float* __restrict__ X, const float* __restrict__ W,
    const float* __restrict__ dinv, float* __restrict__ G, int N) {
  __shared__ float smw[K * 64];
  __shared__ float xs[ROWS * K];
  int tid = threadIdx.x, lane = tid & 63, wv = tid >> 6;
  for (int idx = tid; idx < K * 16; idx += 256)
    ((float4*)smw)[idx] = ((const float4*)W)[idx];
  int row0 = blockIdx.x * ROWS;
  int base = row0 * K;
  int cnt4 = (min(ROWS * K, N * K - base)) >> 2;  // K%4==0 so exact
  const float4* X4 = (const float4*)(X + base);
  for (int idx = tid; idx < cnt4; idx += 256) ((float4*)xs)[idx] = X4[idx];
  __syncthreads();

  constexpr int RW = ROWS / 4;  // rows per wave
  float acc[RW];
#pragma unroll
  for (int r = 0; r < RW; ++r) acc[r] = 0.f;
  const float* xr = &xs[(wv * RW) * K];
#pragma unroll 4
  for (int k = 0; k < K; ++k) {
    float wval = smw[k * 64 + lane];  // lane-contiguous: 2-way bank alias = free
#pragma unroll
    for (int r = 0; r < RW; ++r) acc[r] = fmaf(xr[r * K + k], wval, acc[r]);  // LDS broadcast
  }
#pragma unroll
  for (int r = 0; r < RW; ++r) {
    int row = row0 + wv * RW + r;
    if (row < N) G[(size_t)row * 64 + lane] = acc[r] * dinv[row];
  }
}

// ---------------- aggregation: H[d] = relu(dinv[d]*(G[d] + sum_{s in in(d)} G[s]) + b) ----
// one wave per node; lane = feature. 4-way unroll: 4 independent row-gathers in flight.

__global__ __launch_bounds__(256) void aggregate(
    const float* __restrict__ G, const int* __restrict__ offs,
    const int* __restrict__ srt, const float* __restrict__ dinv,
    const float* __restrict__ bias, float* __restrict__ H, int N) {
  int lane = threadIdx.x & 63, wv = threadIdx.x >> 6;
  int node = blockIdx.x * 4 + wv;
  if (node >= N) return;
  float acc = G[(size_t)node * 64 + lane];  // self loop
  int e = offs[node], e1 = offs[node + 1];
  for (; e + 3 < e1; e += 4) {
    int s0 = srt[e], s1 = srt[e + 1], s2 = srt[e + 2], s3 = srt[e + 3];
    float g0 = G[(size_t)s0 * 64 + lane];
    float g1 = G[(size_t)s1 * 64 + lane];
    float g2 = G[(size_t)s2 * 64 + lane];
    float g3 = G[(size_t)s3 * 64 + lane];
    acc += (g0 + g1) + (g2 + g3);
  }
  for (; e < e1; ++e) acc += G[(size_t)srt[e] * 64 + lane];
  float r = fmaf(acc, dinv[node], bias[lane]);
  H[(size_t)node * 64 + lane] = fmaxf(r, 0.f);
}

// ---------------- classifier: acc6[c] += sum_i H[i]*Wc[i*6+c] ----------------
// LCM(4,6)=12: each thread owns 12 consecutive Wc floats (= 2 rows, 3x float4)
// + float2 of H. 12%6==0 -> class pattern per thread is compile-time static.

__global__ __launch_bounds__(256) void classifier(
    const float* __restrict__ H, const float* __restrict__ Wc,
    float* __restrict__ acc6, int M12) {
  float a[6] = {0.f, 0.f, 0.f, 0.f, 0.f, 0.f};
  int stride = gridDim.x * blockDim.x;
  for (int g = blockIdx.x * blockDim.x + threadIdx.x; g < M12; g += stride) {
    const float4* w4 = (const float4*)Wc + (size_t)g * 3;
    float4 v0 = w4[0];
    float4 v1 = w4[1];
    float4 v2 = w4[2];
    float2 h = ((const float2*)H)[g];
    a[0] = fmaf(h.x, v0.x, a[0]); a[1] = fmaf(h.x, v0.y, a[1]);
    a[2] = fmaf(h.x, v0.z, a[2]); a[3] = fmaf(h.x, v0.w, a[3]);
    a[4] = fmaf(h.x, v1.x, a[4]); a[5] = fmaf(h.x, v1.y, a[5]);
    a[0] = fmaf(h.y, v1.z, a[0]); a[1] = fmaf(h.y, v1.w, a[1]);
    a[2] = fmaf(h.y, v2.x, a[2]); a[3] = fmaf(h.y, v2.y, a[3]);
    a[4] = fmaf(h.y, v2.z, a[4]); a[5] = fmaf(h.y, v2.w, a[5]);
  }
#pragma unroll
  for (int c = 0; c < 6; ++c) {
    for (int d = 32; d > 0; d >>= 1) a[c] += __shfl_down(a[c], d, 64);
  }
  __shared__ float sh[4][6];
  int lane = threadIdx.x & 63, wv = threadIdx.x >> 6;
  if (lane == 0) {
#pragma unroll
    for (int c = 0; c < 6; ++c) sh[wv][c] = a[c];
  }
  __syncthreads();
  if (threadIdx.x == 0) {
#pragma unroll
    for (int c = 0; c < 6; ++c) {
      float t = sh[0][c] + sh[1][c] + sh[2][c] + sh[3][c];
      atomicAdd(&acc6[c], t);
    }
  }
}

__global__ void softmax6(const float* __restrict__ acc6, const float* __restrict__ bc,
                         float* __restrict__ out) {
  if (threadIdx.x == 0) {
    float l[6], m = -1e30f;
#pragma unroll
    for (int c = 0; c < 6; ++c) { l[c] = acc6[c] + bc[c]; m = fmaxf(m, l[c]); }
    float s = 0.f;
#pragma unroll
    for (int c = 0; c < 6; ++c) { l[c] = __expf(l[c] - m); s += l[c]; }
    float inv = 1.f / s;
#pragma unroll
    for (int c = 0; c < 6; ++c) out[c] = l[c] * inv;
  }
}

// ---------------- launch ----------------

extern "C" void kernel_launch(void* const* d_in, const int* in_sizes, int n_in,
                              void* d_out, int out_size, void* d_ws, size_t ws_size,
                              hipStream_t stream) {
  const float* x  = (const float*)d_in[0];
  const int*   ei = (const int*)d_in[1];
  const float* W1 = (const float*)d_in[2];
  const float* b1 = (const float*)d_in[3];
  const float* W2 = (const float*)d_in[4];
  const float* b2 = (const float*)d_in[5];
  const float* Wc = (const float*)d_in[6];
  const float* bc = (const float*)d_in[7];
  float* out = (float*)d_out;

  const int N = in_sizes[0] / 128;  // 50000
  const int E = in_sizes[1] / 2;    // 800000
  const int* esrc = ei;
  const int* edst = ei + E;
  const int nb = (N + 255) / 256;   // 196 (<=256 required by scan_bsums)

  int* deg    = (int*)d_ws;
  int* offs   = deg + N;            // N+1
  int* cursor = offs + N + 1;
  int* srt    = cursor + N;         // E
  int* bsum   = srt + E;            // nb
  float* dinv = (float*)(bsum + nb);
  float* bufA = dinv + N;                      // N*64  (scaled transform g)
  float* bufB = bufA + (size_t)N * 64;         // N*64  (aggregated h)
  float* acc6 = bufB + (size_t)N * 64;         // 6

  hipMemsetAsync(deg, 0, (size_t)N * sizeof(int), stream);
  hipMemsetAsync(acc6, 0, 6 * sizeof(float), stream);

  count_deg<<<(E + 255) / 256, 256, 0, stream>>>(edst, deg, E);
  scan_block<<<nb, 256, 0, stream>>>(deg, offs, bsum, dinv, N);
  scan_bsums<<<1, 256, 0, stream>>>(bsum, offs, nb, N);
  scan_add<<<nb, 256, 0, stream>>>(offs, bsum, cursor, N);
  scatter_edges<<<(E + 255) / 256, 256, 0, stream>>>(esrc, edst, cursor, srt, E);

  gemm_scale<128, 32><<<(N + 31) / 32, 256, 0, stream>>>(x, W1, dinv, bufA, N);
  aggregate<<<(N + 3) / 4, 256, 0, stream>>>(bufA, offs, srt, dinv, b1, bufB, N);
  gemm_scale<64, 32><<<(N + 31) / 32, 256, 0, stream>>>(bufB, W2, dinv, bufA, N);
  aggregate<<<(N + 3) / 4, 256, 0, stream>>>(bufA, offs, srt, dinv, b2, bufB, N);

  // M12 = (N*64*6)/12 = N*32 groups of 12 Wc floats
  classifier<<<2048, 256, 0, stream>>>(bufB, Wc, acc6, N * 32);
  softmax6<<<1, 64, 0, stream>>>(acc6, bc, out);
}

// Round 4
// 252.068 us; speedup vs baseline: 2.4679x; 1.5975x over previous
//
#include <hip/hip_runtime.h>
#include <math.h>

// SensorGNN: 2-layer GCN (N=50000, E=800000, F=128, H=64) + flat classifier (6 classes).
// Pipeline: deg histogram -> prefix scan -> CSR scatter -> [gemm+dinv-scale -> csr-aggregate]x2
//           -> classifier partial dots (no atomics) -> reduce+softmax.
// All f32. Feature buffers (12.8MB) stay L2/L3 resident for the gather phase.
// Round-3 lesson: 12288 same-line atomicAdds serialized cross-XCD (~160us) -> two-stage reduce.

// ---------------- graph build ----------------

__global__ void count_deg(const int* __restrict__ dst, int* __restrict__ deg, int E) {
  int i = blockIdx.x * blockDim.x + threadIdx.x;
  if (i < E) atomicAdd(&deg[dst[i]], 1);
}

// per-256-chunk exclusive scan; bsum[block]=chunk total; dinv = rsqrt(deg+1) (self loop)
__global__ void scan_block(const int* __restrict__ deg, int* __restrict__ offs,
                           int* __restrict__ bsum, float* __restrict__ dinv, int N) {
  int tid = threadIdx.x, lane = tid & 63, wv = tid >> 6;
  int i = blockIdx.x * 256 + tid;
  int v = (i < N) ? deg[i] : 0;
  if (i < N) dinv[i] = rsqrtf((float)(v + 1));
  int x = v;
#pragma unroll
  for (int d = 1; d < 64; d <<= 1) {
    int y = __shfl_up(x, d, 64);
    if (lane >= d) x += y;
  }
  __shared__ int wtot[4];
  __shared__ int woff[4];
  if (lane == 63) wtot[wv] = x;
  __syncthreads();
  if (tid == 0) {
    int s = 0;
    for (int w = 0; w < 4; ++w) { woff[w] = s; s += wtot[w]; }
    bsum[blockIdx.x] = s;
  }
  __syncthreads();
  if (i < N) offs[i] = x - v + woff[wv];
}

// single block: exclusive-scan bsum[nb] in place (nb <= 256), total -> offs[N]
__global__ void scan_bsums(int* __restrict__ bsum, int* __restrict__ offs, int nb, int N) {
  int tid = threadIdx.x, lane = tid & 63, wv = tid >> 6;
  int v = (tid < nb) ? bsum[tid] : 0;
  int x = v;
#pragma unroll
  for (int d = 1; d < 64; d <<= 1) {
    int y = __shfl_up(x, d, 64);
    if (lane >= d) x += y;
  }
  __shared__ int wtot[4];
  __shared__ int woff[4];
  if (lane == 63) wtot[wv] = x;
  __syncthreads();
  if (tid == 0) {
    int s = 0;
    for (int w = 0; w < 4; ++w) { woff[w] = s; s += wtot[w]; }
  }
  __syncthreads();
  int excl = x - v + woff[wv];
  if (tid < nb) bsum[tid] = excl;
  if (tid == nb - 1) offs[N] = excl + v;
}

__global__ void scan_add(int* __restrict__ offs, const int* __restrict__ bsum,
                         int* __restrict__ cursor, int N) {
  int i = blockIdx.x * 256 + threadIdx.x;
  if (i < N) {
    int o = offs[i] + bsum[blockIdx.x];
    offs[i] = o;
    cursor[i] = o;
  }
}

__global__ void scatter_edges(const int* __restrict__ src, const int* __restrict__ dst,
                              int* __restrict__ cursor, int* __restrict__ srt, int E) {
  int i = blockIdx.x * blockDim.x + threadIdx.x;
  if (i < E) {
    int p = atomicAdd(&cursor[dst[i]], 1);
    srt[p] = src[i];
  }
}

// ---------------- dense transform: G = (X @ W) * dinv[row] ----------------
// block = 256 (4 waves), 32 rows/block, each wave computes 8 rows x 64 cols.
// Unroll capped at 4 to avoid the round-1 VGPR blowup (256 VGPR + 380MB scratch spill).

template <int K, int ROWS>
__global__ __launch_bounds__(256) void gemm_scale(
    const float* __restrict__ X, const float* __restrict__ W,
    const float* __restrict__ dinv, float* __restrict__ G, int N) {
  __shared__ float smw[K * 64];
  __shared__ float xs[ROWS * K];
  int tid = threadIdx.x, lane = tid & 63, wv = tid >> 6;
  for (int idx = tid; idx < K * 16; idx += 256)
    ((float4*)smw)[idx] = ((const float4*)W)[idx];
  int row0 = blockIdx.x * ROWS;
  int base = row0 * K;
  int cnt4 = (min(ROWS * K, N * K - base)) >> 2;  // K%4==0 so exact
  const float4* X4 = (const float4*)(X + base);
  for (int idx = tid; idx < cnt4; idx += 256) ((float4*)xs)[idx] = X4[idx];
  __syncthreads();

  constexpr int RW = ROWS / 4;  // rows per wave
  float acc[RW];
#pragma unroll
  for (int r = 0; r < RW; ++r) acc[r] = 0.f;
  const float* xr = &xs[(wv * RW) * K];
#pragma unroll 4
  for (int k = 0; k < K; ++k) {
    float wval = smw[k * 64 + lane];  // lane-contiguous: 2-way bank alias = free
#pragma unroll
    for (int r = 0; r < RW; ++r) acc[r] = fmaf(xr[r * K + k], wval, acc[r]);  // LDS broadcast
  }
#pragma unroll
  for (int r = 0; r < RW; ++r) {
    int row = row0 + wv * RW + r;
    if (row < N) G[(size_t)row * 64 + lane] = acc[r] * dinv[row];
  }
}

// ---------------- aggregation: H[d] = relu(dinv[d]*(G[d] + sum_{s in in(d)} G[s]) + b) ----
// one wave per node; lane = feature. 4-way unroll: 4 independent row-gathers in flight.

__global__ __launch_bounds__(256) void aggregate(
    const float* __restrict__ G, const int* __restrict__ offs,
    const int* __restrict__ srt, const float* __restrict__ dinv,
    const float* __restrict__ bias, float* __restrict__ H, int N) {
  int lane = threadIdx.x & 63, wv = threadIdx.x >> 6;
  int node = blockIdx.x * 4 + wv;
  if (node >= N) return;
  float acc = G[(size_t)node * 64 + lane];  // self loop
  int e = offs[node], e1 = offs[node + 1];
  for (; e + 3 < e1; e += 4) {
    int s0 = srt[e], s1 = srt[e + 1], s2 = srt[e + 2], s3 = srt[e + 3];
    float g0 = G[(size_t)s0 * 64 + lane];
    float g1 = G[(size_t)s1 * 64 + lane];
    float g2 = G[(size_t)s2 * 64 + lane];
    float g3 = G[(size_t)s3 * 64 + lane];
    acc += (g0 + g1) + (g2 + g3);
  }
  for (; e < e1; ++e) acc += G[(size_t)srt[e] * 64 + lane];
  float r = fmaf(acc, dinv[node], bias[lane]);
  H[(size_t)node * 64 + lane] = fmaxf(r, 0.f);
}

// ---------------- classifier: part[b][c] = block-partial of sum_i H[i]*Wc[i*6+c] --------
// LCM(4,6)=12: each thread owns 12 consecutive Wc floats (= 2 rows, 3x float4)
// + float2 of H. 12%6==0 -> class pattern per thread is compile-time static.
// NO atomics: per-block partials, reduced by reduce_softmax (round-3: atomic tail was 160us).

__global__ __launch_bounds__(256) void classifier(
    const float* __restrict__ H, const float* __restrict__ Wc,
    float* __restrict__ part, int M12) {
  float a[6] = {0.f, 0.f, 0.f, 0.f, 0.f, 0.f};
  int stride = gridDim.x * blockDim.x;
  for (int g = blockIdx.x * blockDim.x + threadIdx.x; g < M12; g += stride) {
    const float4* w4 = (const float4*)Wc + (size_t)g * 3;
    float4 v0 = w4[0];
    float4 v1 = w4[1];
    float4 v2 = w4[2];
    float2 h = ((const float2*)H)[g];
    a[0] = fmaf(h.x, v0.x, a[0]); a[1] = fmaf(h.x, v0.y, a[1]);
    a[2] = fmaf(h.x, v0.z, a[2]); a[3] = fmaf(h.x, v0.w, a[3]);
    a[4] = fmaf(h.x, v1.x, a[4]); a[5] = fmaf(h.x, v1.y, a[5]);
    a[0] = fmaf(h.y, v1.z, a[0]); a[1] = fmaf(h.y, v1.w, a[1]);
    a[2] = fmaf(h.y, v2.x, a[2]); a[3] = fmaf(h.y, v2.y, a[3]);
    a[4] = fmaf(h.y, v2.z, a[4]); a[5] = fmaf(h.y, v2.w, a[5]);
  }
#pragma unroll
  for (int c = 0; c < 6; ++c) {
    for (int d = 32; d > 0; d >>= 1) a[c] += __shfl_down(a[c], d, 64);
  }
  __shared__ float sh[4][6];
  int lane = threadIdx.x & 63, wv = threadIdx.x >> 6;
  if (lane == 0) {
#pragma unroll
    for (int c = 0; c < 6; ++c) sh[wv][c] = a[c];
  }
  __syncthreads();
  if (threadIdx.x == 0) {
#pragma unroll
    for (int c = 0; c < 6; ++c)
      part[(size_t)blockIdx.x * 6 + c] = sh[0][c] + sh[1][c] + sh[2][c] + sh[3][c];
  }
}

// single block: sum part[nb][6], add bias, softmax, write out[6]
__global__ __launch_bounds__(256) void reduce_softmax(
    const float* __restrict__ part, int nb,
    const float* __restrict__ bc, float* __restrict__ out) {
  int tid = threadIdx.x, lane = tid & 63, wv = tid >> 6;
  float a[6] = {0.f, 0.f, 0.f, 0.f, 0.f, 0.f};
  for (int b = tid; b < nb; b += 256) {
    const float* p = part + (size_t)b * 6;
#pragma unroll
    for (int c = 0; c < 6; ++c) a[c] += p[c];
  }
#pragma unroll
  for (int c = 0; c < 6; ++c) {
    for (int d = 32; d > 0; d >>= 1) a[c] += __shfl_down(a[c], d, 64);
  }
  __shared__ float sh[4][6];
  if (lane == 0) {
#pragma unroll
    for (int c = 0; c < 6; ++c) sh[wv][c] = a[c];
  }
  __syncthreads();
  if (tid == 0) {
    float l[6], m = -1e30f;
#pragma unroll
    for (int c = 0; c < 6; ++c) {
      l[c] = sh[0][c] + sh[1][c] + sh[2][c] + sh[3][c] + bc[c];
      m = fmaxf(m, l[c]);
    }
    float s = 0.f;
#pragma unroll
    for (int c = 0; c < 6; ++c) { l[c] = __expf(l[c] - m); s += l[c]; }
    float inv = 1.f / s;
#pragma unroll
    for (int c = 0; c < 6; ++c) out[c] = l[c] * inv;
  }
}

// ---------------- launch ----------------

static inline size_t align4up(size_t x) { return (x + 3) & ~(size_t)3; }  // 4-elem = 16B

extern "C" void kernel_launch(void* const* d_in, const int* in_sizes, int n_in,
                              void* d_out, int out_size, void* d_ws, size_t ws_size,
                              hipStream_t stream) {
  const float* x  = (const float*)d_in[0];
  const int*   ei = (const int*)d_in[1];
  const float* W1 = (const float*)d_in[2];
  const float* b1 = (const float*)d_in[3];
  const float* W2 = (const float*)d_in[4];
  const float* b2 = (const float*)d_in[5];
  const float* Wc = (const float*)d_in[6];
  const float* bc = (const float*)d_in[7];
  float* out = (float*)d_out;

  const int N = in_sizes[0] / 128;  // 50000
  const int E = in_sizes[1] / 2;    // 800000
  const int* esrc = ei;
  const int* edst = ei + E;
  const int nb = (N + 255) / 256;   // 196 (<=256 required by scan_bsums)
  const int CGRID = 2048;           // classifier blocks

  // 16B-aligned workspace carve (bufB was 4B-misaligned for float2 in round 2/3)
  size_t o = 0;
  int* deg    = (int*)d_ws + o;           o = align4up(o + N);
  int* offs   = (int*)d_ws + o;           o = align4up(o + N + 1);
  int* cursor = (int*)d_ws + o;           o = align4up(o + N);
  int* srt    = (int*)d_ws + o;           o = align4up(o + E);
  int* bsum   = (int*)d_ws + o;           o = align4up(o + nb);
  float* dinv = (float*)d_ws + o;         o = align4up(o + N);
  float* bufA = (float*)d_ws + o;         o = align4up(o + (size_t)N * 64);
  float* bufB = (float*)d_ws + o;         o = align4up(o + (size_t)N * 64);
  float* part = (float*)d_ws + o;         o = align4up(o + (size_t)CGRID * 6);

  hipMemsetAsync(deg, 0, (size_t)N * sizeof(int), stream);

  count_deg<<<(E + 255) / 256, 256, 0, stream>>>(edst, deg, E);
  scan_block<<<nb, 256, 0, stream>>>(deg, offs, bsum, dinv, N);
  scan_bsums<<<1, 256, 0, stream>>>(bsum, offs, nb, N);
  scan_add<<<nb, 256, 0, stream>>>(offs, bsum, cursor, N);
  scatter_edges<<<(E + 255) / 256, 256, 0, stream>>>(esrc, edst, cursor, srt, E);

  gemm_scale<128, 32><<<(N + 31) / 32, 256, 0, stream>>>(x, W1, dinv, bufA, N);
  aggregate<<<(N + 3) / 4, 256, 0, stream>>>(bufA, offs, srt, dinv, b1, bufB, N);
  gemm_scale<64, 32><<<(N + 31) / 32, 256, 0, stream>>>(bufB, W2, dinv, bufA, N);
  aggregate<<<(N + 3) / 4, 256, 0, stream>>>(bufA, offs, srt, dinv, b2, bufB, N);

  // M12 = (N*64*6)/12 = N*32 groups of 12 Wc floats
  classifier<<<CGRID, 256, 0, stream>>>(bufB, Wc, part, N * 32);
  reduce_softmax<<<1, 256, 0, stream>>>(part, CGRID, bc, out);
}

// Round 5
// 246.298 us; speedup vs baseline: 2.5257x; 1.0234x over previous
//
#include <hip/hip_runtime.h>
#include <math.h>

// SensorGNN: 2-layer GCN (N=50000, E=800000, F=128, H=64) + flat classifier (6 classes).
// Pipeline: deg histogram -> prefix scan -> CSR scatter -> [gemm+dinv-scale -> csr-aggregate]x2
//           -> classifier partial dots (no atomics) -> reduce+softmax.
// All f32. Feature buffers (12.8MB) stay L2/L3 resident for the gather phase.
// Round-3 lesson: 12288 same-line atomicAdds serialized cross-XCD (~160us) -> two-stage reduce.
// Round-4 lesson: scatter/count latency-bound (VALUBusy 0.4%) -> 4 edges/thread ILP.

// ---------------- graph build ----------------

__global__ void count_deg(const int* __restrict__ dst, int* __restrict__ deg, int E) {
  int i = blockIdx.x * blockDim.x + threadIdx.x;
  int e0 = i * 4;
  if (e0 + 3 < E) {
    int4 d = ((const int4*)dst)[i];
    atomicAdd(&deg[d.x], 1);
    atomicAdd(&deg[d.y], 1);
    atomicAdd(&deg[d.z], 1);
    atomicAdd(&deg[d.w], 1);
  } else {
    for (int e = e0; e < E; ++e) atomicAdd(&deg[dst[e]], 1);
  }
}

// per-256-chunk exclusive scan; bsum[block]=chunk total; dinv = rsqrt(deg+1) (self loop)
__global__ void scan_block(const int* __restrict__ deg, int* __restrict__ offs,
                           int* __restrict__ bsum, float* __restrict__ dinv, int N) {
  int tid = threadIdx.x, lane = tid & 63, wv = tid >> 6;
  int i = blockIdx.x * 256 + tid;
  int v = (i < N) ? deg[i] : 0;
  if (i < N) dinv[i] = rsqrtf((float)(v + 1));
  int x = v;
#pragma unroll
  for (int d = 1; d < 64; d <<= 1) {
    int y = __shfl_up(x, d, 64);
    if (lane >= d) x += y;
  }
  __shared__ int wtot[4];
  __shared__ int woff[4];
  if (lane == 63) wtot[wv] = x;
  __syncthreads();
  if (tid == 0) {
    int s = 0;
    for (int w = 0; w < 4; ++w) { woff[w] = s; s += wtot[w]; }
    bsum[blockIdx.x] = s;
  }
  __syncthreads();
  if (i < N) offs[i] = x - v + woff[wv];
}

// single block: exclusive-scan bsum[nb] in place (nb <= 256), total -> offs[N]
__global__ void scan_bsums(int* __restrict__ bsum, int* __restrict__ offs, int nb, int N) {
  int tid = threadIdx.x, lane = tid & 63, wv = tid >> 6;
  int v = (tid < nb) ? bsum[tid] : 0;
  int x = v;
#pragma unroll
  for (int d = 1; d < 64; d <<= 1) {
    int y = __shfl_up(x, d, 64);
    if (lane >= d) x += y;
  }
  __shared__ int wtot[4];
  __shared__ int woff[4];
  if (lane == 63) wtot[wv] = x;
  __syncthreads();
  if (tid == 0) {
    int s = 0;
    for (int w = 0; w < 4; ++w) { woff[w] = s; s += wtot[w]; }
  }
  __syncthreads();
  int excl = x - v + woff[wv];
  if (tid < nb) bsum[tid] = excl;
  if (tid == nb - 1) offs[N] = excl + v;
}

__global__ void scan_add(int* __restrict__ offs, const int* __restrict__ bsum,
                         int* __restrict__ cursor, int N) {
  int i = blockIdx.x * 256 + threadIdx.x;
  if (i < N) {
    int o = offs[i] + bsum[blockIdx.x];
    offs[i] = o;
    cursor[i] = o;
  }
}

__global__ void scatter_edges(const int* __restrict__ src, const int* __restrict__ dst,
                              int* __restrict__ cursor, int* __restrict__ srt, int E) {
  int i = blockIdx.x * blockDim.x + threadIdx.x;
  int e0 = i * 4;
  if (e0 + 3 < E) {
    int4 s = ((const int4*)src)[i];
    int4 d = ((const int4*)dst)[i];
    int p0 = atomicAdd(&cursor[d.x], 1);
    int p1 = atomicAdd(&cursor[d.y], 1);
    int p2 = atomicAdd(&cursor[d.z], 1);
    int p3 = atomicAdd(&cursor[d.w], 1);
    srt[p0] = s.x;
    srt[p1] = s.y;
    srt[p2] = s.z;
    srt[p3] = s.w;
  } else {
    for (int e = e0; e < E; ++e) {
      int p = atomicAdd(&cursor[dst[e]], 1);
      srt[p] = src[e];
    }
  }
}

// ---------------- dense transform: G = (X @ W) * dinv[row] ----------------
// block = 256 (4 waves), 32 rows/block, each wave computes 8 rows x 64 cols.
// Unroll capped at 4 to avoid the round-1 VGPR blowup (256 VGPR + 380MB scratch spill).

template <int K, int ROWS>
__global__ __launch_bounds__(256) void gemm_scale(
    const float* __restrict__ X, const float* __restrict__ W,
    const float* __restrict__ dinv, float* __restrict__ G, int N) {
  __shared__ float smw[K * 64];
  __shared__ float xs[ROWS * K];
  int tid = threadIdx.x, lane = tid & 63, wv = tid >> 6;
  for (int idx = tid; idx < K * 16; idx += 256)
    ((float4*)smw)[idx] = ((const float4*)W)[idx];
  int row0 = blockIdx.x * ROWS;
  int base = row0 * K;
  int cnt4 = (min(ROWS * K, N * K - base)) >> 2;  // K%4==0 so exact
  const float4* X4 = (const float4*)(X + base);
  for (int idx = tid; idx < cnt4; idx += 256) ((float4*)xs)[idx] = X4[idx];
  __syncthreads();

  constexpr int RW = ROWS / 4;  // rows per wave
  float acc[RW];
#pragma unroll
  for (int r = 0; r < RW; ++r) acc[r] = 0.f;
  const float* xr = &xs[(wv * RW) * K];
#pragma unroll 4
  for (int k = 0; k < K; ++k) {
    float wval = smw[k * 64 + lane];  // lane-contiguous: 2-way bank alias = free
#pragma unroll
    for (int r = 0; r < RW; ++r) acc[r] = fmaf(xr[r * K + k], wval, acc[r]);  // LDS broadcast
  }
#pragma unroll
  for (int r = 0; r < RW; ++r) {
    int row = row0 + wv * RW + r;
    if (row < N) G[(size_t)row * 64 + lane] = acc[r] * dinv[row];
  }
}

// ---------------- aggregation: H[d] = relu(dinv[d]*(G[d] + sum_{s in in(d)} G[s]) + b) ----
// one wave per node. lane = sub*16 + fl: sub in [0,4) picks which of 4 concurrent edges,
// fl in [0,16) picks the float4 feature quad. 4 edges (4x256B rows) in flight per iteration;
// cross-sub reduce via 2x shfl_xor at the end.

__global__ __launch_bounds__(256) void aggregate(
    const float* __restrict__ G, const int* __restrict__ offs,
    const int* __restrict__ srt, const float* __restrict__ dinv,
    const float* __restrict__ bias, float* __restrict__ H, int N) {
  int lane = threadIdx.x & 63, wv = threadIdx.x >> 6;
  int sub = lane >> 4, fl = lane & 15;
  int node = blockIdx.x * 4 + wv;
  if (node >= N) return;
  const float4* G4 = (const float4*)G;

  // self loop owned by sub 0
  float4 acc;
  if (sub == 0) acc = G4[(size_t)node * 16 + fl];
  else          acc = make_float4(0.f, 0.f, 0.f, 0.f);

  int e = offs[node], e1 = offs[node + 1];
  for (; e + 3 < e1; e += 4) {
    int s = srt[e + sub];                     // 4 distinct ints/wave, broadcast within sub
    float4 g = G4[(size_t)s * 16 + fl];       // 4 rows x 256B fetched concurrently
    acc.x += g.x; acc.y += g.y; acc.z += g.z; acc.w += g.w;
  }
  int rem = e1 - e;
  if (sub < rem) {
    int s = srt[e + sub];
    float4 g = G4[(size_t)s * 16 + fl];
    acc.x += g.x; acc.y += g.y; acc.z += g.z; acc.w += g.w;
  }

  // reduce across the 4 sub groups (lanes fl, fl+16, fl+32, fl+48)
#pragma unroll
  for (int m = 16; m < 64; m <<= 1) {
    acc.x += __shfl_xor(acc.x, m, 64);
    acc.y += __shfl_xor(acc.y, m, 64);
    acc.z += __shfl_xor(acc.z, m, 64);
    acc.w += __shfl_xor(acc.w, m, 64);
  }

  if (sub == 0) {
    float dn = dinv[node];
    const float4* b4 = (const float4*)bias;
    float4 bb = b4[fl];
    float4 r;
    r.x = fmaxf(fmaf(acc.x, dn, bb.x), 0.f);
    r.y = fmaxf(fmaf(acc.y, dn, bb.y), 0.f);
    r.z = fmaxf(fmaf(acc.z, dn, bb.z), 0.f);
    r.w = fmaxf(fmaf(acc.w, dn, bb.w), 0.f);
    ((float4*)H)[(size_t)node * 16 + fl] = r;
  }
}

// ---------------- classifier: part[b][c] = block-partial of sum_i H[i]*Wc[i*6+c] --------
// LCM(4,6)=12: each thread owns 12 consecutive Wc floats (= 2 rows, 3x float4)
// + float2 of H. 12%6==0 -> class pattern per thread is compile-time static.
// NO atomics: per-block partials, reduced by reduce_softmax (round-3: atomic tail was 160us).

__global__ __launch_bounds__(256) void classifier(
    const float* __restrict__ H, const float* __restrict__ Wc,
    float* __restrict__ part, int M12) {
  float a[6] = {0.f, 0.f, 0.f, 0.f, 0.f, 0.f};
  int stride = gridDim.x * blockDim.x;
  for (int g = blockIdx.x * blockDim.x + threadIdx.x; g < M12; g += stride) {
    const float4* w4 = (const float4*)Wc + (size_t)g * 3;
    float4 v0 = w4[0];
    float4 v1 = w4[1];
    float4 v2 = w4[2];
    float2 h = ((const float2*)H)[g];
    a[0] = fmaf(h.x, v0.x, a[0]); a[1] = fmaf(h.x, v0.y, a[1]);
    a[2] = fmaf(h.x, v0.z, a[2]); a[3] = fmaf(h.x, v0.w, a[3]);
    a[4] = fmaf(h.x, v1.x, a[4]); a[5] = fmaf(h.x, v1.y, a[5]);
    a[0] = fmaf(h.y, v1.z, a[0]); a[1] = fmaf(h.y, v1.w, a[1]);
    a[2] = fmaf(h.y, v2.x, a[2]); a[3] = fmaf(h.y, v2.y, a[3]);
    a[4] = fmaf(h.y, v2.z, a[4]); a[5] = fmaf(h.y, v2.w, a[5]);
  }
#pragma unroll
  for (int c = 0; c < 6; ++c) {
    for (int d = 32; d > 0; d >>= 1) a[c] += __shfl_down(a[c], d, 64);
  }
  __shared__ float sh[4][6];
  int lane = threadIdx.x & 63, wv = threadIdx.x >> 6;
  if (lane == 0) {
#pragma unroll
    for (int c = 0; c < 6; ++c) sh[wv][c] = a[c];
  }
  __syncthreads();
  if (threadIdx.x == 0) {
#pragma unroll
    for (int c = 0; c < 6; ++c)
      part[(size_t)blockIdx.x * 6 + c] = sh[0][c] + sh[1][c] + sh[2][c] + sh[3][c];
  }
}

// single block: sum part[nb][6], add bias, softmax, write out[6]
__global__ __launch_bounds__(256) void reduce_softmax(
    const float* __restrict__ part, int nb,
    const float* __restrict__ bc, float* __restrict__ out) {
  int tid = threadIdx.x, lane = tid & 63, wv = tid >> 6;
  float a[6] = {0.f, 0.f, 0.f, 0.f, 0.f, 0.f};
  for (int b = tid; b < nb; b += 256) {
    const float* p = part + (size_t)b * 6;
#pragma unroll
    for (int c = 0; c < 6; ++c) a[c] += p[c];
  }
#pragma unroll
  for (int c = 0; c < 6; ++c) {
    for (int d = 32; d > 0; d >>= 1) a[c] += __shfl_down(a[c], d, 64);
  }
  __shared__ float sh[4][6];
  if (lane == 0) {
#pragma unroll
    for (int c = 0; c < 6; ++c) sh[wv][c] = a[c];
  }
  __syncthreads();
  if (tid == 0) {
    float l[6], m = -1e30f;
#pragma unroll
    for (int c = 0; c < 6; ++c) {
      l[c] = sh[0][c] + sh[1][c] + sh[2][c] + sh[3][c] + bc[c];
      m = fmaxf(m, l[c]);
    }
    float s = 0.f;
#pragma unroll
    for (int c = 0; c < 6; ++c) { l[c] = __expf(l[c] - m); s += l[c]; }
    float inv = 1.f / s;
#pragma unroll
    for (int c = 0; c < 6; ++c) out[c] = l[c] * inv;
  }
}

// ---------------- launch ----------------

static inline size_t align4up(size_t x) { return (x + 3) & ~(size_t)3; }  // 4-elem = 16B

extern "C" void kernel_launch(void* const* d_in, const int* in_sizes, int n_in,
                              void* d_out, int out_size, void* d_ws, size_t ws_size,
                              hipStream_t stream) {
  const float* x  = (const float*)d_in[0];
  const int*   ei = (const int*)d_in[1];
  const float* W1 = (const float*)d_in[2];
  const float* b1 = (const float*)d_in[3];
  const float* W2 = (const float*)d_in[4];
  const float* b2 = (const float*)d_in[5];
  const float* Wc = (const float*)d_in[6];
  const float* bc = (const float*)d_in[7];
  float* out = (float*)d_out;

  const int N = in_sizes[0] / 128;  // 50000
  const int E = in_sizes[1] / 2;    // 800000
  const int* esrc = ei;
  const int* edst = ei + E;
  const int nb = (N + 255) / 256;   // 196 (<=256 required by scan_bsums)
  const int CGRID = 2048;           // classifier blocks
  const int E4 = (E + 3) / 4;       // edge quads for ILP kernels

  // 16B-aligned workspace carve
  size_t o = 0;
  int* deg    = (int*)d_ws + o;           o = align4up(o + N);
  int* offs   = (int*)d_ws + o;           o = align4up(o + N + 1);
  int* cursor = (int*)d_ws + o;           o = align4up(o + N);
  int* srt    = (int*)d_ws + o;           o = align4up(o + E);
  int* bsum   = (int*)d_ws + o;           o = align4up(o + nb);
  float* dinv = (float*)d_ws + o;         o = align4up(o + N);
  float* bufA = (float*)d_ws + o;         o = align4up(o + (size_t)N * 64);
  float* bufB = (float*)d_ws + o;         o = align4up(o + (size_t)N * 64);
  float* part = (float*)d_ws + o;         o = align4up(o + (size_t)CGRID * 6);

  hipMemsetAsync(deg, 0, (size_t)N * sizeof(int), stream);

  count_deg<<<(E4 + 255) / 256, 256, 0, stream>>>(edst, deg, E);
  scan_block<<<nb, 256, 0, stream>>>(deg, offs, bsum, dinv, N);
  scan_bsums<<<1, 256, 0, stream>>>(bsum, offs, nb, N);
  scan_add<<<nb, 256, 0, stream>>>(offs, bsum, cursor, N);
  scatter_edges<<<(E4 + 255) / 256, 256, 0, stream>>>(esrc, edst, cursor, srt, E);

  gemm_scale<128, 32><<<(N + 31) / 32, 256, 0, stream>>>(x, W1, dinv, bufA, N);
  aggregate<<<(N + 3) / 4, 256, 0, stream>>>(bufA, offs, srt, dinv, b1, bufB, N);
  gemm_scale<64, 32><<<(N + 31) / 32, 256, 0, stream>>>(bufB, W2, dinv, bufA, N);
  aggregate<<<(N + 3) / 4, 256, 0, stream>>>(bufA, offs, srt, dinv, b2, bufB, N);

  // M12 = (N*64*6)/12 = N*32 groups of 12 Wc floats
  classifier<<<CGRID, 256, 0, stream>>>(bufB, Wc, part, N * 32);
  reduce_softmax<<<1, 256, 0, stream>>>(part, CGRID, bc, out);
}